// Round 1
// 106.972 us; speedup vs baseline: 1.1552x; 1.1552x over previous
//
#include <hip/hip_runtime.h>
#include <math.h>

// Gaussian splatting forward rasterizer, MI355X.
// P=2048 gaussians, 128x128 image. Output: img (3*128*128 f32) ++ radii (P f32).
//
// R6 (this round):
//  - prep Phase A: depth-only sort keys. valid == (depth > 0.2) because
//    det = (C00+.3)(C11+.3) - C01^2 >= .3*(C00+C11)+.09 (cov2d PSD) -- the
//    PSD margin is ~1e3, fp32 error ~1e-3, so det>0 ALWAYS holds (in the
//    reference too). Removes 32x2048 redundant full projection chains
//    (~12 divides each) from Phase A.
//  - raster: wave-parallel cull. Lane l tests gaussian h+l against the tile
//    (one coalesced float4 load from a compact cull array), __ballot ->
//    wave-uniform 64-bit hit mask, then a ctz bit-loop composites only the
//    ~2-3 hits per (tile,chunk) in ascending-rank (= front-to-back) order.
//    Replaces the serial 64-iteration cull loop (~800 instr/wave -> ~190).
//  - K=16 chunks (chunk=128, 1024 blocks = 4/CU): halves the `part`
//    partial-buffer round trip.

#define IMG 128
#define NPIX (IMG * IMG)
#define GS 12        // record: px py ca cb cc op r g b r2 pad pad
#define SORT_N 2048

// ---------------------------------------------------------- projection chain
__device__ __forceinline__ void gproj(int i,
                                      const float* __restrict__ means,
                                      const float* __restrict__ rots,
                                      const float* __restrict__ scales,
                                      const float* __restrict__ vm,
                                      const float* __restrict__ pm,
                                      float& depth, bool& valid,
                                      float& px, float& py,
                                      float& ca, float& cb, float& cc,
                                      float& lam)
{
    const float W = (float)IMG, H = (float)IMG;
    const float tanfov = 0.5773502691896258f;        // tan(FOV/2)
    const float focal_x = W / (2.0f * tanfov);
    const float focal_y = H / (2.0f * tanfov);
    const float lim = 1.3f * tanfov;

    float mx = means[3 * i + 0], my = means[3 * i + 1], mz = means[3 * i + 2];

    float tx = vm[0] * mx + vm[1] * my + vm[2]  * mz + vm[3];
    float ty = vm[4] * mx + vm[5] * my + vm[6]  * mz + vm[7];
    float tz = vm[8] * mx + vm[9] * my + vm[10] * mz + vm[11];
    depth = tz;

    float ph0 = pm[0]  * mx + pm[1]  * my + pm[2]  * mz + pm[3];
    float ph1 = pm[4]  * mx + pm[5]  * my + pm[6]  * mz + pm[7];
    float pw  = pm[12] * mx + pm[13] * my + pm[14] * mz + pm[15];
    float rinv = 1.0f / (pw + 1e-7f);
    px = ((ph0 * rinv + 1.0f) * W - 1.0f) * 0.5f;
    py = ((ph1 * rinv + 1.0f) * H - 1.0f) * 0.5f;

    float qw = rots[4 * i + 0], qx = rots[4 * i + 1], qy = rots[4 * i + 2], qz = rots[4 * i + 3];
    float qn = sqrtf(qw * qw + qx * qx + qy * qy + qz * qz);
    qw /= qn; qx /= qn; qy /= qn; qz /= qn;
    float R00 = 1.0f - 2.0f * (qy * qy + qz * qz), R01 = 2.0f * (qx * qy - qw * qz), R02 = 2.0f * (qx * qz + qw * qy);
    float R10 = 2.0f * (qx * qy + qw * qz), R11 = 1.0f - 2.0f * (qx * qx + qz * qz), R12 = 2.0f * (qy * qz - qw * qx);
    float R20 = 2.0f * (qx * qz - qw * qy), R21 = 2.0f * (qy * qz + qw * qx), R22 = 1.0f - 2.0f * (qx * qx + qy * qy);

    float sx = scales[3 * i + 0], sy = scales[3 * i + 1], sz = scales[3 * i + 2];
    float M00 = R00 * sx, M01 = R01 * sy, M02 = R02 * sz;
    float M10 = R10 * sx, M11 = R11 * sy, M12 = R12 * sz;
    float M20 = R20 * sx, M21 = R21 * sy, M22 = R22 * sz;
    float S00 = M00 * M00 + M01 * M01 + M02 * M02;
    float S01 = M00 * M10 + M01 * M11 + M02 * M12;
    float S02 = M00 * M20 + M01 * M21 + M02 * M22;
    float S11 = M10 * M10 + M11 * M11 + M12 * M12;
    float S12 = M10 * M20 + M11 * M21 + M12 * M22;
    float S22 = M20 * M20 + M21 * M21 + M22 * M22;

    float txc = fminf(fmaxf(tx / tz, -lim), lim) * tz;
    float tyc = fminf(fmaxf(ty / tz, -lim), lim) * tz;
    float J00 = focal_x / tz, J02 = -focal_x * txc / (tz * tz);
    float J11 = focal_y / tz, J12 = -focal_y * tyc / (tz * tz);

    float T00 = J00 * vm[0] + J02 * vm[8];
    float T01 = J00 * vm[1] + J02 * vm[9];
    float T02 = J00 * vm[2] + J02 * vm[10];
    float T10 = J11 * vm[4] + J12 * vm[8];
    float T11 = J11 * vm[5] + J12 * vm[9];
    float T12 = J11 * vm[6] + J12 * vm[10];

    float U00 = T00 * S00 + T01 * S01 + T02 * S02;
    float U01 = T00 * S01 + T01 * S11 + T02 * S12;
    float U02 = T00 * S02 + T01 * S12 + T02 * S22;
    float U10 = T10 * S00 + T11 * S01 + T12 * S02;
    float U11 = T10 * S01 + T11 * S11 + T12 * S12;
    float U12 = T10 * S02 + T11 * S12 + T12 * S22;
    float C00 = U00 * T00 + U01 * T01 + U02 * T02;
    float C01 = U00 * T10 + U01 * T11 + U02 * T12;
    float C11 = U10 * T10 + U11 * T11 + U12 * T12;

    float a = C00 + 0.3f, b = C01, c = C11 + 0.3f;
    float det = a * c - b * b;
    valid = (depth > 0.2f) && (det > 0.0f);
    float det_s = valid ? det : 1.0f;
    ca = c / det_s; cb = -b / det_s; cc = a / det_s;

    float mid = 0.5f * (a + c);
    lam = mid + sqrtf(fmaxf(mid * mid - det, 0.1f));
}

// ------------------------------------------- fused preprocess + rank + scatter
__global__ void gsplat_prep_rank_scatter(const float* __restrict__ means,
                                         const float* __restrict__ feats,
                                         const float* __restrict__ ops,
                                         const float* __restrict__ scales,
                                         const float* __restrict__ rots,
                                         const float* __restrict__ vm,
                                         const float* __restrict__ pm,
                                         float* __restrict__ gS,
                                         float4* __restrict__ culls,
                                         float* __restrict__ radii_out,
                                         int P)
{
    __shared__ unsigned int sk[SORT_N];
    __shared__ int partial[256];
    int tid = threadIdx.x;

    // Phase A: every block computes ALL depth keys. valid == depth>0.2
    // (det>0 always, see header) so the key needs only the view-z row:
    // 3 fma per gaussian instead of the full projection chain.
    #pragma unroll 2
    for (int j = tid; j < SORT_N; j += 256) {
        unsigned int key = 0xFFFFFFFFu;                  // pad sorts last
        if (j < P) {
            float mx = means[3 * j + 0], my = means[3 * j + 1], mz = means[3 * j + 2];
            float tz = vm[8] * mx + vm[9] * my + vm[10] * mz + vm[11];
            key = (tz > 0.2f) ? __float_as_uint(tz) : 0x7f800000u; // +inf invalid
        }
        sk[j] = key;
    }
    __syncthreads();

    // Phase B: stable rank for this block's 64 gaussians (4 key-slices x 64).
    int g = tid & 63, s = tid >> 6;
    int i = blockIdx.x * 64 + g;
    bool act = (i < P);
    unsigned int ki = act ? sk[i] : 0u;

    const int SLICE = SORT_N / 4;
    int j0 = s * SLICE;
    const uint4* sk4 = (const uint4*)(sk + j0);
    int r = 0;
    #pragma unroll 4
    for (int q = 0; q < SLICE / 4; ++q) {
        uint4 k = sk4[q];                                // wave-broadcast
        int j = j0 + 4 * q;
        r += (k.x < ki) || (k.x == ki && (j + 0) < i);
        r += (k.y < ki) || (k.y == ki && (j + 1) < i);
        r += (k.z < ki) || (k.z == ki && (j + 2) < i);
        r += (k.w < ki) || (k.w == ki && (j + 3) < i);
    }
    partial[tid] = r;
    __syncthreads();

    // Phase C: full record for own gaussian -> sorted slot; radii in orig order.
    if (s == 0 && act) {
        int rank = partial[g] + partial[64 + g] + partial[128 + g] + partial[192 + g];

        float depth, px, py, ca, cb, cc, lam; bool valid;
        gproj(i, means, rots, scales, vm, pm, depth, valid, px, py, ca, cb, cc, lam);

        const float SH_C0 = 0.28209479177387814f;
        float colr = fmaxf(SH_C0 * feats[3 * i + 0] + 0.5f, 0.0f);
        float colg = fmaxf(SH_C0 * feats[3 * i + 1] + 0.5f, 0.0f);
        float colb = fmaxf(SH_C0 * feats[3 * i + 2] + 0.5f, 0.0f);

        float opv = ops[i];
        float r2;
        if (valid) {
            // alpha >= 1/255 requires d^2 <= 2*lam_max*ln(255*op) (exact bound)
            r2 = 2.0f * lam * __logf(255.0f * opv) * 1.02f + 0.5f;
        } else {
            px = 0.0f; py = 0.0f; ca = 0.0f; cb = 0.0f; cc = 0.0f;
            opv = 0.0f; r2 = -1.0f;                      // never composited
        }
        radii_out[i] = valid ? ceilf(3.0f * sqrtf(lam)) : 0.0f;

        float4* dst = (float4*)(gS + (size_t)rank * GS);
        dst[0] = make_float4(px, py, ca, cb);
        dst[1] = make_float4(cc, opv, colr, colg);
        dst[2] = make_float4(colb, r2, 0.0f, 0.0f);
        culls[rank] = make_float4(px, py, r2, 0.0f);     // compact cull record
    }
}

// ----------------------------------------------------------------- raster
// Block = (tile, chunk); one thread per pixel of a 16x16 tile. Wave-parallel
// cull: lane l tests gaussian h+l (coalesced float4 load), __ballot gives a
// wave-uniform hit mask; the ctz bit-loop composites only the hits, in
// ascending-rank (front-to-back) order. Record loads inside the bit-loop are
// wave-uniform -> scalar loads.
__global__ void gsplat_raster_chunk(const float* __restrict__ gS,
                                    const float4* __restrict__ culls,
                                    int P, int chunk, float4* __restrict__ part)
{
    int lx = threadIdx.x & 15, ly = threadIdx.x >> 4;
    int lane = threadIdx.x & 63;
    int tilex = blockIdx.x & 7, tiley = blockIdx.x >> 3;
    int x = tilex * 16 + lx, y = tiley * 16 + ly;
    float gx = (float)x, gy = (float)y;
    float tx0 = (float)(tilex * 16), tx1 = (float)(tilex * 16 + 15);
    float ty0 = (float)(tiley * 16), ty1 = (float)(tiley * 16 + 15);

    int base = blockIdx.y * chunk;
    int cnt = min(chunk, P - base);

    float T = 1.0f, cr = 0.0f, cg = 0.0f, cb = 0.0f;
    const float* Gp = gS + (size_t)base * GS;

    for (int h = 0; h < chunk; h += 64) {
        int gi = h + lane;
        bool pred = false;
        if (gi < cnt) {
            float4 cu = culls[base + gi];
            // nearest tile point vs r2 bound (same exact test as before)
            float ddx = cu.x - fminf(fmaxf(cu.x, tx0), tx1);
            float ddy = cu.y - fminf(fmaxf(cu.y, ty0), ty1);
            pred = (ddx * ddx + ddy * ddy <= cu.z);
        }
        unsigned long long m = __ballot(pred);           // wave-uniform mask
        while (m) {
            int b = __builtin_ctzll(m);                  // ascending rank
            m &= m - 1;
            const float* G = Gp + (size_t)(h + b) * GS;  // uniform -> s_load
            float pxv = G[0], pyv = G[1];
            float ca = G[2], cbn = G[3], cc = G[4];
            float op = G[5], r = G[6], g = G[7], bl = G[8];
            float dx = gx - pxv, dy = gy - pyv;
            float power = -0.5f * (ca * dx * dx + cc * dy * dy) - cbn * dx * dy;
            float e = __expf(fminf(power, 0.0f));
            float alpha = fminf(0.99f, op * e);
            alpha = (power > 0.0f) ? 0.0f : alpha;
            alpha = (alpha < 0.00392156862745098f) ? 0.0f : alpha;
            float w = T * alpha;
            cr = fmaf(w, r, cr);
            cg = fmaf(w, g, cg);
            cb = fmaf(w, bl, cb);
            T = T * (1.0f - alpha);
        }
    }

    int pix = y * IMG + x;
    part[(size_t)blockIdx.y * NPIX + pix] = make_float4(cr, cg, cb, T);
}

// ----------------------------------------------------------------- combine
// Ordered front-to-back merge of K chunk partials per pixel; adds T_final.
__global__ void gsplat_combine(const float4* __restrict__ part, int K,
                               float* __restrict__ img)
{
    int pix = blockIdx.x * blockDim.x + threadIdx.x;
    if (pix >= NPIX) return;
    float T = 1.0f, r = 0.0f, g = 0.0f, b = 0.0f;
    for (int c = 0; c < K; ++c) {
        float4 v = part[(size_t)c * NPIX + pix];
        r = fmaf(T, v.x, r);
        g = fmaf(T, v.y, g);
        b = fmaf(T, v.z, b);
        T *= v.w;
    }
    img[pix]            = r + T;
    img[NPIX + pix]     = g + T;
    img[2 * NPIX + pix] = b + T;
}

// ------------------------------------------------------------------ launch
extern "C" void kernel_launch(void* const* d_in, const int* in_sizes, int n_in,
                              void* d_out, int out_size, void* d_ws, size_t ws_size,
                              hipStream_t stream)
{
    const float* means  = (const float*)d_in[0];
    const float* feats  = (const float*)d_in[2];
    const float* ops    = (const float*)d_in[3];
    const float* scales = (const float*)d_in[4];
    const float* rots   = (const float*)d_in[5];
    const float* vm     = (const float*)d_in[6];
    const float* pm     = (const float*)d_in[7];

    int P = in_sizes[0] / 3;   // 2048

    float* img   = (float*)d_out;            // 3*128*128
    float* radii = (float*)d_out + 3 * NPIX; // P

    float*  gS    = (float*)d_ws;                        // SORT_N*GS floats
    float4* culls = (float4*)(gS + (size_t)SORT_N * GS); // SORT_N float4
    float4* part  = culls + SORT_N;
    size_t static_bytes = (size_t)SORT_N * (GS + 4) * sizeof(float);

    // Pick K chunks to fit ws: part needs K*NPIX*16 bytes.
    int K = 16;
    while (K > 1 && static_bytes + (size_t)K * NPIX * sizeof(float4) > ws_size) K >>= 1;
    int chunk = (P + K - 1) / K;
    chunk = (chunk + 63) & ~63;              // h-loop walks 64-gaussian groups
    int Kb = (P + chunk - 1) / chunk;        // actual chunk-block count

    gsplat_prep_rank_scatter<<<(P + 63) / 64, 256, 0, stream>>>(
        means, feats, ops, scales, rots, vm, pm, gS, culls, radii, P);

    gsplat_raster_chunk<<<dim3(64, Kb), 256, 0, stream>>>(gS, culls, P, chunk, part);

    gsplat_combine<<<NPIX / 256, 256, 0, stream>>>(part, Kb, img);
}